// Round 18
// baseline (127.149 us; speedup 1.0000x reference)
//
#include <hip/hip_runtime.h>
#include <cstdint>

typedef unsigned uint;
typedef unsigned short u16;
typedef int v4i  __attribute__((ext_vector_type(4)));
typedef int v16i __attribute__((ext_vector_type(16)));
typedef float v2f __attribute__((ext_vector_type(2)));

// d_ws word layout:
//   [0,144)       w1 signs as +-1.0f
//   [144,1424)    W2B: conv2 weight frags, f=s*64+l: oc=l&31, tap=2s+(l>>5), ic=e
//   [1424,3728)   W3B: conv3 weight frags, f=s*64+l: oc=l&31, tap=s, ic=(l>>5)*16+e
//   [3728,8568)   wfc packed to 22x22 grid, PERMUTED bit order (see bitpos)
static constexpr int WS_W2B = 144;
static constexpr int WS_W3B = 1424;
static constexpr int WS_FC  = 3728;

// LDS layout, 20368B (20480 granule; proven neutral-to-R12, kept).
// Region A [0,18432):
//   conv1:  xs f32[784] [0,3136) + h1 i8[676][16] [3136,13952)
//   conv2:  reads h1; writes h2w u16[576][2] into gap [13952,16256)
//   expand: reads h2w to 3 named regs, barrier, writes h2 i8[2][576][16]
//   FC:     red uint[4][5] at [0,80), lg float[10] at [80,120) (A dead)
// Region B [18432,20368): h3 uint[484] (conv3 out / FC in)
static constexpr int L_XS  = 0;
static constexpr int L_H1  = 3136;
static constexpr int L_H2  = 0;
static constexpr int L_H2B = 13952;
static constexpr int L_H3  = 18432;
static constexpr int L_RED = 0;
static constexpr int L_LG  = 80;
static constexpr int L_TOT = 20368;

// Permuted bit position for channel c in h2w/h3 words:
// lane-half h = c[2], reg r = (c&3) + 4*(c>>3); bitpos = 16h + r.
__device__ __host__ __forceinline__ int bitpos32(int c) {
    return (((c >> 2) & 1) << 4) + (c & 3) + ((c >> 3) << 2);
}

__global__ __launch_bounds__(256) void pack_kernel(
    const float* __restrict__ w1, const float* __restrict__ w2,
    const float* __restrict__ w3, const float* __restrict__ wfc,
    uint* __restrict__ wsu)
{
    int gid = blockIdx.x * 256 + threadIdx.x;
    if (gid < 144) {
        ((float*)wsu)[gid] = (w1[gid] >= 0.f) ? 1.f : -1.f;
    } else if (gid < 464) {
        // conv2 weight frag (A-operand): oc = l&31, tap = 2s+(l>>5), ic = e
        int f = gid - 144, s = f >> 6, l = f & 63;
        int oc = l & 31, tap = s * 2 + (l >> 5);
        uint w[4] = {0u, 0u, 0u, 0u};
        if (tap < 9) {
            for (int e = 0; e < 16; ++e) {
                uint b = (w2[(oc * 16 + e) * 9 + tap] >= 0.f) ? 0x01u : 0xFFu;
                w[e >> 2] |= b << (8 * (e & 3));
            }
        }
        for (int j = 0; j < 4; ++j) wsu[WS_W2B + f * 4 + j] = w[j];
    } else if (gid < 1040) {
        // conv3 weight frag (A-operand): oc = l&31, tap = s, ic = (l>>5)*16+e
        int f = gid - 464, s = f >> 6, l = f & 63;
        int oc = l & 31, icb = (l >> 5) * 16;
        uint w[4] = {0u, 0u, 0u, 0u};
        for (int e = 0; e < 16; ++e) {
            uint b = (w3[(oc * 32 + icb + e) * 9 + s] >= 0.f) ? 0x01u : 0xFFu;
            w[e >> 2] |= b << (8 * (e & 3));
        }
        for (int j = 0; j < 4; ++j) wsu[WS_W3B + f * 4 + j] = w[j];
    } else if (gid < 5880) {
        // FC weights, bit order matching conv3's per-lane mask build.
        int f = gid - 1040, o = f / 484, p = f % 484;
        int Y = p / 22, X = p % 22;
        const float* base = wfc + o * 3872 + (Y >> 1) * 11 + (X >> 1);
        uint bits = 0;
        for (int c = 0; c < 32; ++c)
            bits |= (base[c * 121] >= 0.f ? 1u : 0u) << bitpos32(c);
        wsu[WS_FC + f] = bits;
    }
}

// 4 sign bits -> 4 i8 bytes (bit=1 -> +1, bit=0 -> -1)
__device__ __forceinline__ int expand4(uint t) {
    return (int)~(((t * 0x00204081u) & 0x01010101u) * 0xFEu);
}
__device__ __forceinline__ v4i expand16(uint bits) {
    v4i r;
    r[0] = expand4(bits & 0xFu);
    r[1] = expand4((bits >> 4) & 0xFu);
    r[2] = expand4((bits >> 8) & 0xFu);
    r[3] = expand4((bits >> 12) & 0xFu);
    return r;
}
// Unpack one permuted h2w word into half-split h2 (lo at p, hi at 9216+p).
__device__ __forceinline__ void expand_store(signed char* h2, int p, uint w) {
    v4i lo, hi;
    lo[0] = expand4( w        & 0xFu);
    lo[1] = expand4((w >> 16) & 0xFu);
    lo[2] = expand4((w >>  4) & 0xFu);
    lo[3] = expand4((w >> 20) & 0xFu);
    hi[0] = expand4((w >>  8) & 0xFu);
    hi[1] = expand4((w >> 24) & 0xFu);
    hi[2] = expand4((w >> 12) & 0xFu);
    hi[3] = expand4((w >> 28) & 0xFu);
    *(v4i*)(h2 + p*16)        = lo;   // ic 0-15
    *(v4i*)(h2 + 9216 + p*16) = hi;   // ic 16-31
}

// One paired conv1 step: xp[9] = (rowA, rowB) window pairs for two output
// rows; returns the two 16-bit channel masks via m0/m1. fp32 fast path,
// merged rare fp64 fallback (inline, no double arrays).
__device__ __forceinline__ void conv1_pair(
    const float* __restrict__ wf, const v2f* xp, uint& m0, uint& m1)
{
    m0 = 0; m1 = 0;
    for (int oc = 0; oc < 16; ++oc) {
        v2f s = {0.f, 0.f};
        #pragma unroll
        for (int k = 0; k < 9; ++k)
            s = xp[k] * wf[oc*9 + k] + s;      // v_pk_fma_f32
        bool b0 = (s.x >= 0.f), b1 = (s.y >= 0.f);
        // fp32 accum error bound ~2.9e-5 << 1e-4: outside the band the
        // fp32 sign equals the exact (fp64) sign.
        if (__builtin_expect(fmaxf(fabsf(s.x), fabsf(s.y)) < 1e-4f, 0)) {
            double d0 = 0.0, d1 = 0.0;
            for (int k = 0; k < 9; ++k) {
                double w = (double)wf[oc*9 + k];
                d0 += (double)xp[k].x * w;
                d1 += (double)xp[k].y * w;
            }
            b0 = (d0 >= 0.0); b1 = (d1 >= 0.0);
        }
        m0 |= (uint)b0 << oc;
        m1 |= (uint)b1 << oc;
    }
}

__global__ __launch_bounds__(256) void binet_kernel(
    const float* __restrict__ x, const uint* __restrict__ wsu,
    const float* __restrict__ bfc, float* __restrict__ out)
{
    __shared__ __align__(16) unsigned char lds[L_TOT];
    const int t = threadIdx.x;
    const int img = blockIdx.x;
    const int l = t & 63, wave = t >> 6, half = l >> 5, lane31 = l & 31;

    float* xs = (float*)(lds + L_XS);
    signed char* h1 = (signed char*)(lds + L_H1);
    signed char* h2 = (signed char*)(lds + L_H2);
    u16*  h2u = (u16*)(lds + L_H2B);
    uint* h2w = (uint*)(lds + L_H2B);
    u16*  h3u = (u16*)(lds + L_H3);
    uint* h3  = (uint*)(lds + L_H3);
    uint (*red)[5] = (uint(*)[5])(lds + L_RED);
    float* lg = (float*)(lds + L_LG);

    // ---- load image ----
    {
        const float* xin = x + (size_t)img * 784;
        for (int i = t; i < 784; i += 256) xs[i] = xin[i];
    }
    __syncthreads();

    // ---- conv1: 4 rows/thread in TWO passes of paired-2 (only xp[9]=18
    // regs live). Thread (g=t/26, xcol=t%26) owns output rows 4g..4g+3
    // (g=6: rows 24,25 only -> passB skipped). 182 active threads, no
    // clamps needed anywhere.
    if (t < 182) {
        const float* wf = (const float*)wsu;   // uniform -> scalar loads
        const int g = t / 26, xcol = t - g * 26;
        const int y0 = 4 * g;
        v2f xp[9];
        float r3[3];
        // passA window: input rows y0..y0+3 (<= 27 for g=6: rows 24..27 ok)
        #pragma unroll
        for (int c = 0; c < 3; ++c) {
            float a0 = xs[(y0    )*28 + xcol + c];
            float a1 = xs[(y0 + 1)*28 + xcol + c];
            float a2 = xs[(y0 + 2)*28 + xcol + c];
            float a3 = xs[(y0 + 3)*28 + xcol + c];
            v2f p;
            p.x = a0; p.y = a1; xp[c]     = p;
            p.x = a1; p.y = a2; xp[3 + c] = p;
            p.x = a2; p.y = a3; xp[6 + c] = p;
            r3[c] = a3;
        }
        uint m0, m1;
        conv1_pair(wf, xp, m0, m1);
        *(v4i*)(h1 + ((y0    )*26 + xcol)*16) = expand16(m0);
        *(v4i*)(h1 + ((y0 + 1)*26 + xcol)*16) = expand16(m1);
        // passB: output rows y0+2, y0+3; window rows y0+2..y0+5.
        if (g < 6) {
            #pragma unroll
            for (int c = 0; c < 3; ++c) {
                float a4 = xs[(y0 + 4)*28 + xcol + c];
                float a5 = xs[(y0 + 5)*28 + xcol + c];
                xp[c] = xp[6 + c];                 // rows y0+2, y0+3
                v2f p;
                p.x = r3[c]; p.y = a4; xp[3 + c] = p;   // rows y0+3, y0+4
                p.x = a4;    p.y = a5; xp[6 + c] = p;   // rows y0+4, y0+5
            }
            conv1_pair(wf, xp, m0, m1);
            *(v4i*)(h1 + ((y0 + 2)*26 + xcol)*16) = expand16(m0);
            *(v4i*)(h1 + ((y0 + 3)*26 + xcol)*16) = expand16(m1);
        }
    }
    __syncthreads();

    // ---- conv2 via i8 MFMA, SWAPPED operands: D[oc][pos] ----
    {
        const v4i* w2bp = (const v4i*)(wsu + WS_W2B);
        v4i b2f[5];
        #pragma unroll
        for (int s = 0; s < 5; ++s) b2f[s] = w2bp[s*64 + l];
        for (int tile = wave; tile < 18; tile += 4) {
            const int mb = tile * 32;
            const int row = mb + lane31;
            const int y = row / 24, xx = row % 24;
            v16i acc = {0,0,0,0,0,0,0,0,0,0,0,0,0,0,0,0};
            #pragma unroll
            for (int s = 0; s < 5; ++s) {
                int tap = s*2 + half; if (tap > 8) tap = 8;  // W zeroed for tap 9
                int ky = tap / 3, kx = tap - ky*3;
                v4i b = *(const v4i*)(h1 + ((y+ky)*26 + xx+kx)*16);
                acc = __builtin_amdgcn_mfma_i32_32x32x32_i8(b2f[s], b, acc, 0, 0, 0);
            }
            uint mneg = 0;
            #pragma unroll
            for (int r = 0; r < 16; ++r)
                mneg |= (((uint)acc[r]) >> 31) << r;   // bit r = sign(oc(r,half))
            h2u[row*2 + half] = (u16)~mneg;
        }
    }
    __syncthreads();

    // ---- expand h2w -> h2 i8[2][576][16]: 3 named regs -> barrier -> write
    {
        uint w0 = h2w[t];
        uint w1 = h2w[t + 256];
        uint w2 = (t < 64) ? h2w[t + 512] : 0u;
        __syncthreads();
        expand_store(h2, t, w0);
        expand_store(h2, t + 256, w1);
        if (t < 64) expand_store(h2, t + 512, w2);
    }
    __syncthreads();

    // ---- conv3 via i8 MFMA, SWAPPED operands: D[oc][pos] ----
    {
        const v4i* w3bp = (const v4i*)(wsu + WS_W3B);
        v4i b3f[9];
        #pragma unroll
        for (int s = 0; s < 9; ++s) b3f[s] = w3bp[s*64 + l];
        const signed char* h2h = h2 + half*9216;
        for (int tile = wave; tile < 16; tile += 4) {
            const int mb = tile * 32;
            int row = mb + lane31;
            int pr = (row < 484) ? row : 483;
            const int y = pr / 22, xx = pr % 22;
            v16i acc = {0,0,0,0,0,0,0,0,0,0,0,0,0,0,0,0};
            #pragma unroll
            for (int s = 0; s < 9; ++s) {
                const int ky = s / 3, kx = s - ky*3;
                v4i b = *(const v4i*)(h2h + ((y+ky)*24 + xx+kx)*16);
                acc = __builtin_amdgcn_mfma_i32_32x32x32_i8(b3f[s], b, acc, 0, 0, 0);
            }
            uint mneg = 0;
            #pragma unroll
            for (int r = 0; r < 16; ++r)
                mneg |= (((uint)acc[r]) >> 31) << r;
            if (row < 484) h3u[row*2 + half] = (u16)~mneg;
        }
    }
    __syncthreads();

    // ---- avgpool + FC as binary dot (permuted bits match wfc packing) ----
    uint acc5[5] = {0u, 0u, 0u, 0u, 0u};
    for (int p = t; p < 484; p += 256) {
        uint h = h3[p];
        const uint* wp = wsu + WS_FC + p;
        #pragma unroll
        for (int o = 0; o < 5; ++o)
            acc5[o] += (uint)__popc(h ^ wp[(2*o)*484])
                     + ((uint)__popc(h ^ wp[(2*o+1)*484]) << 16);
    }
    #pragma unroll
    for (int o = 0; o < 5; ++o) {
        uint v = acc5[o];
        v += __shfl_down(v, 32); v += __shfl_down(v, 16);
        v += __shfl_down(v, 8);  v += __shfl_down(v, 4);
        v += __shfl_down(v, 2);  v += __shfl_down(v, 1);
        acc5[o] = v;
    }
    if (l == 0) {
        #pragma unroll
        for (int o = 0; o < 5; ++o) red[wave][o] = acc5[o];
    }
    __syncthreads();
    if (t < 10) {
        uint S = 0;
        #pragma unroll
        for (int j = 0; j < 4; ++j) {
            uint w = red[j][t >> 1];
            S += (t & 1) ? (w >> 16) : (w & 0xFFFFu);
        }
        lg[t] = 0.25f * (float)(15488 - 2*(int)S) + bfc[t];
    }
    __syncthreads();
    if (t < 10) {
        float m = lg[0];
        #pragma unroll
        for (int o = 1; o < 10; ++o) m = fmaxf(m, lg[o]);
        float se = 0.f;
        #pragma unroll
        for (int o = 0; o < 10; ++o) se += expf(lg[o] - m);
        out[(size_t)img*10 + t] = lg[t] - m - logf(se);
    }
}

extern "C" void kernel_launch(void* const* d_in, const int* in_sizes, int n_in,
                              void* d_out, int out_size, void* d_ws, size_t ws_size,
                              hipStream_t stream)
{
    const float* x   = (const float*)d_in[0];
    const float* w1  = (const float*)d_in[1];
    const float* w2  = (const float*)d_in[2];
    const float* w3  = (const float*)d_in[3];
    const float* wfc = (const float*)d_in[4];
    const float* bfc = (const float*)d_in[5];
    float* out = (float*)d_out;
    uint* wsu  = (uint*)d_ws;

    const int B = in_sizes[0] / 784;   // 8192

    hipLaunchKernelGGL(pack_kernel, dim3(23), dim3(256), 0, stream,
                       w1, w2, w3, wfc, wsu);
    hipLaunchKernelGGL(binet_kernel, dim3(B), dim3(256), 0, stream,
                       x, wsu, bfc, out);
}

// Round 19
// 110.394 us; speedup vs baseline: 1.1518x; 1.1518x over previous
//
#include <hip/hip_runtime.h>
#include <cstdint>

typedef unsigned uint;
typedef unsigned short u16;
typedef int v4i  __attribute__((ext_vector_type(4)));
typedef int v16i __attribute__((ext_vector_type(16)));
typedef float v2f __attribute__((ext_vector_type(2)));

// d_ws word layout:
//   [0,144)       w1 signs as +-1.0f
//   [144,1424)    W2B: conv2 weight frags, f=s*64+l: oc=l&31, tap=2s+(l>>5), ic=e
//   [1424,3728)   W3B: conv3 weight frags, f=s*64+l: oc=l&31, tap=s, ic=(l>>5)*16+e
//   [3728,8568)   wfc packed to 22x22 grid, PERMUTED bit order (see bitpos)
static constexpr int WS_W2B = 144;
static constexpr int WS_W3B = 1424;
static constexpr int WS_FC  = 3728;

// LDS layout, 20368B (20480 granule).
// Region A [0,18432):
//   conv1:  xs f32[784] [0,3136) + h1 i8[676][16] [3136,13952)
//   conv2:  reads h1; writes h2w u16[576][2] into gap [13952,16256)
//   expand: reads h2w to 3 named regs, barrier, writes h2 i8[2][576][16]
//   FC:     red uint[4][5] at [0,80), lg float[10] at [80,120) (A dead)
// Region B [18432,20368): h3 uint[484] (conv3 out / FC in)
static constexpr int L_XS  = 0;
static constexpr int L_H1  = 3136;
static constexpr int L_H2  = 0;
static constexpr int L_H2B = 13952;
static constexpr int L_H3  = 18432;
static constexpr int L_RED = 0;
static constexpr int L_LG  = 80;
static constexpr int L_TOT = 20368;

// Permuted bit position for channel c in h2w/h3 words:
// lane-half h = c[2], reg r = (c&3) + 4*(c>>3); bitpos = 16h + r.
__device__ __host__ __forceinline__ int bitpos32(int c) {
    return (((c >> 2) & 1) << 4) + (c & 3) + ((c >> 3) << 2);
}

__global__ __launch_bounds__(256) void pack_kernel(
    const float* __restrict__ w1, const float* __restrict__ w2,
    const float* __restrict__ w3, const float* __restrict__ wfc,
    uint* __restrict__ wsu)
{
    int gid = blockIdx.x * 256 + threadIdx.x;
    if (gid < 144) {
        ((float*)wsu)[gid] = (w1[gid] >= 0.f) ? 1.f : -1.f;
    } else if (gid < 464) {
        // conv2 weight frag (A-operand): oc = l&31, tap = 2s+(l>>5), ic = e
        int f = gid - 144, s = f >> 6, l = f & 63;
        int oc = l & 31, tap = s * 2 + (l >> 5);
        uint w[4] = {0u, 0u, 0u, 0u};
        if (tap < 9) {
            for (int e = 0; e < 16; ++e) {
                uint b = (w2[(oc * 16 + e) * 9 + tap] >= 0.f) ? 0x01u : 0xFFu;
                w[e >> 2] |= b << (8 * (e & 3));
            }
        }
        for (int j = 0; j < 4; ++j) wsu[WS_W2B + f * 4 + j] = w[j];
    } else if (gid < 1040) {
        // conv3 weight frag (A-operand): oc = l&31, tap = s, ic = (l>>5)*16+e
        int f = gid - 464, s = f >> 6, l = f & 63;
        int oc = l & 31, icb = (l >> 5) * 16;
        uint w[4] = {0u, 0u, 0u, 0u};
        for (int e = 0; e < 16; ++e) {
            uint b = (w3[(oc * 32 + icb + e) * 9 + s] >= 0.f) ? 0x01u : 0xFFu;
            w[e >> 2] |= b << (8 * (e & 3));
        }
        for (int j = 0; j < 4; ++j) wsu[WS_W3B + f * 4 + j] = w[j];
    } else if (gid < 5880) {
        // FC weights, bit order matching conv3's per-lane mask build.
        int f = gid - 1040, o = f / 484, p = f % 484;
        int Y = p / 22, X = p % 22;
        const float* base = wfc + o * 3872 + (Y >> 1) * 11 + (X >> 1);
        uint bits = 0;
        for (int c = 0; c < 32; ++c)
            bits |= (base[c * 121] >= 0.f ? 1u : 0u) << bitpos32(c);
        wsu[WS_FC + f] = bits;
    }
}

// 4 sign bits -> 4 i8 bytes (bit=1 -> +1, bit=0 -> -1)
__device__ __forceinline__ int expand4(uint t) {
    return (int)~(((t * 0x00204081u) & 0x01010101u) * 0xFEu);
}
__device__ __forceinline__ v4i expand16(uint bits) {
    v4i r;
    r[0] = expand4(bits & 0xFu);
    r[1] = expand4((bits >> 4) & 0xFu);
    r[2] = expand4((bits >> 8) & 0xFu);
    r[3] = expand4((bits >> 12) & 0xFu);
    return r;
}
// Unpack one permuted h2w word into half-split h2 (lo at p, hi at 9216+p).
__device__ __forceinline__ void expand_store(signed char* h2, int p, uint w) {
    v4i lo, hi;
    lo[0] = expand4( w        & 0xFu);
    lo[1] = expand4((w >> 16) & 0xFu);
    lo[2] = expand4((w >>  4) & 0xFu);
    lo[3] = expand4((w >> 20) & 0xFu);
    hi[0] = expand4((w >>  8) & 0xFu);
    hi[1] = expand4((w >> 24) & 0xFu);
    hi[2] = expand4((w >> 12) & 0xFu);
    hi[3] = expand4((w >> 28) & 0xFu);
    *(v4i*)(h2 + p*16)        = lo;   // ic 0-15
    *(v4i*)(h2 + 9216 + p*16) = hi;   // ic 16-31
}

__global__ __launch_bounds__(256) void binet_kernel(
    const float* __restrict__ x, const uint* __restrict__ wsu,
    const float* __restrict__ bfc, float* __restrict__ out)
{
    __shared__ __align__(16) unsigned char lds[L_TOT];
    const int t = threadIdx.x;
    const int img = blockIdx.x;
    const int l = t & 63, wave = t >> 6, half = l >> 5, lane31 = l & 31;

    float* xs = (float*)(lds + L_XS);
    signed char* h1 = (signed char*)(lds + L_H1);
    signed char* h2 = (signed char*)(lds + L_H2);
    u16*  h2u = (u16*)(lds + L_H2B);
    uint* h2w = (uint*)(lds + L_H2B);
    u16*  h3u = (u16*)(lds + L_H3);
    uint* h3  = (uint*)(lds + L_H3);
    uint (*red)[5] = (uint(*)[5])(lds + L_RED);
    float* lg = (float*)(lds + L_LG);

    // ---- load image ----
    {
        const float* xin = x + (size_t)img * 784;
        for (int i = t; i < 784; i += 256) xs[i] = xin[i];
    }
    __syncthreads();

    // ---- conv1 (R12-proven): 3 rows/thread, pk-fma pair + scalar third;
    // merged rare fp64 fallback. Thread (g=t/26, xcol=t%26), rows 3g..3g+2.
    if (t < 234) {
        const float* wf = (const float*)wsu;   // uniform -> scalar loads
        const int g = t / 26, xcol = t - g * 26;
        const int y0 = 3 * g;
        float xv[5][3];
        #pragma unroll
        for (int r = 0; r < 5; ++r) {
            int rr = y0 + r; if (rr > 27) rr = 27;   // g=8 clamp (rows unused)
            #pragma unroll
            for (int c = 0; c < 3; ++c)
                xv[r][c] = xs[rr*28 + xcol + c];
        }
        v2f xp[9];
        #pragma unroll
        for (int ky = 0; ky < 3; ++ky)
            #pragma unroll
            for (int kx = 0; kx < 3; ++kx) {
                v2f p; p.x = xv[ky][kx]; p.y = xv[ky+1][kx];
                xp[ky*3+kx] = p;
            }
        uint m0 = 0, m1 = 0, m2 = 0;
        for (int oc = 0; oc < 16; ++oc) {
            v2f s01 = {0.f, 0.f};
            float s2 = 0.f;
            #pragma unroll
            for (int ky = 0; ky < 3; ++ky)
                #pragma unroll
                for (int kx = 0; kx < 3; ++kx) {
                    float w = wf[oc*9 + ky*3 + kx];
                    s01 = xp[ky*3+kx] * w + s01;          // v_pk_fma_f32
                    s2  = fmaf(xv[ky + 2][kx], w, s2);
                }
            float s0 = s01.x, s1 = s01.y;
            bool b0 = (s0 >= 0.f), b1 = (s1 >= 0.f), b2 = (s2 >= 0.f);
            // fp32 accum error bound ~2.9e-5 << 1e-4: outside the band the
            // fp32 sign equals the exact (fp64) sign.
            if (__builtin_expect((int)((fabsf(s0) < 1e-4f) |
                                       (fabsf(s1) < 1e-4f) |
                                       (fabsf(s2) < 1e-4f)), 0)) {
                double d0 = 0.0, d1 = 0.0, d2 = 0.0;
                for (int k = 0; k < 9; ++k) {
                    double w = (double)wf[oc*9 + k];
                    d0 += (double)xv[k/3    ][k%3] * w;
                    d1 += (double)xv[k/3 + 1][k%3] * w;
                    d2 += (double)xv[k/3 + 2][k%3] * w;
                }
                b0 = (d0 >= 0.0); b1 = (d1 >= 0.0); b2 = (d2 >= 0.0);
            }
            m0 |= (uint)b0 << oc;
            m1 |= (uint)b1 << oc;
            m2 |= (uint)b2 << oc;
        }
        *(v4i*)(h1 + ((y0    )*26 + xcol)*16) = expand16(m0);
        *(v4i*)(h1 + ((y0 + 1)*26 + xcol)*16) = expand16(m1);
        if (y0 + 2 <= 25)
            *(v4i*)(h1 + ((y0 + 2)*26 + xcol)*16) = expand16(m2);
    }
    __syncthreads();

    // ---- conv2 via i8 MFMA, SWAPPED operands: D[oc][pos] ----
    {
        const v4i* w2bp = (const v4i*)(wsu + WS_W2B);
        v4i b2f[5];
        #pragma unroll
        for (int s = 0; s < 5; ++s) b2f[s] = w2bp[s*64 + l];
        for (int tile = wave; tile < 18; tile += 4) {
            const int mb = tile * 32;
            const int row = mb + lane31;
            const int y = row / 24, xx = row % 24;
            v16i acc = {0,0,0,0,0,0,0,0,0,0,0,0,0,0,0,0};
            #pragma unroll
            for (int s = 0; s < 5; ++s) {
                int tap = s*2 + half; if (tap > 8) tap = 8;  // W zeroed for tap 9
                int ky = tap / 3, kx = tap - ky*3;
                v4i b = *(const v4i*)(h1 + ((y+ky)*26 + xx+kx)*16);
                acc = __builtin_amdgcn_mfma_i32_32x32x32_i8(b2f[s], b, acc, 0, 0, 0);
            }
            uint mneg = 0;
            #pragma unroll
            for (int r = 0; r < 16; ++r)
                mneg |= (((uint)acc[r]) >> 31) << r;   // bit r = sign(oc(r,half))
            h2u[row*2 + half] = (u16)~mneg;
        }
    }
    __syncthreads();

    // ---- expand h2w -> h2 i8[2][576][16]: 3 named regs -> barrier -> write
    {
        uint w0 = h2w[t];
        uint w1 = h2w[t + 256];
        uint w2 = (t < 64) ? h2w[t + 512] : 0u;
        __syncthreads();
        expand_store(h2, t, w0);
        expand_store(h2, t + 256, w1);
        if (t < 64) expand_store(h2, t + 512, w2);
    }
    __syncthreads();

    // ---- conv3 via i8 MFMA, SWAPPED operands: D[oc][pos] ----
    {
        const v4i* w3bp = (const v4i*)(wsu + WS_W3B);
        v4i b3f[9];
        #pragma unroll
        for (int s = 0; s < 9; ++s) b3f[s] = w3bp[s*64 + l];
        const signed char* h2h = h2 + half*9216;
        for (int tile = wave; tile < 16; tile += 4) {
            const int mb = tile * 32;
            int row = mb + lane31;
            int pr = (row < 484) ? row : 483;
            const int y = pr / 22, xx = pr % 22;
            v16i acc = {0,0,0,0,0,0,0,0,0,0,0,0,0,0,0,0};
            #pragma unroll
            for (int s = 0; s < 9; ++s) {
                const int ky = s / 3, kx = s - ky*3;
                v4i b = *(const v4i*)(h2h + ((y+ky)*24 + xx+kx)*16);
                acc = __builtin_amdgcn_mfma_i32_32x32x32_i8(b3f[s], b, acc, 0, 0, 0);
            }
            uint mneg = 0;
            #pragma unroll
            for (int r = 0; r < 16; ++r)
                mneg |= (((uint)acc[r]) >> 31) << r;
            if (row < 484) h3u[row*2 + half] = (u16)~mneg;
        }
    }
    __syncthreads();

    // ---- avgpool + FC as binary dot (permuted bits match wfc packing) ----
    uint acc5[5] = {0u, 0u, 0u, 0u, 0u};
    for (int p = t; p < 484; p += 256) {
        uint h = h3[p];
        const uint* wp = wsu + WS_FC + p;
        #pragma unroll
        for (int o = 0; o < 5; ++o)
            acc5[o] += (uint)__popc(h ^ wp[(2*o)*484])
                     + ((uint)__popc(h ^ wp[(2*o+1)*484]) << 16);
    }
    #pragma unroll
    for (int o = 0; o < 5; ++o) {
        uint v = acc5[o];
        v += __shfl_down(v, 32); v += __shfl_down(v, 16);
        v += __shfl_down(v, 8);  v += __shfl_down(v, 4);
        v += __shfl_down(v, 2);  v += __shfl_down(v, 1);
        acc5[o] = v;
    }
    if (l == 0) {
        #pragma unroll
        for (int o = 0; o < 5; ++o) red[wave][o] = acc5[o];
    }
    __syncthreads();
    // ---- S-sum, log-softmax, out: all within wave 0 (t<10). Intra-wave
    // LDS ordering (compiler lgkmcnt) makes lg[] writes visible to the
    // same wave's reads without a block barrier.
    if (t < 10) {
        uint S = 0;
        #pragma unroll
        for (int j = 0; j < 4; ++j) {
            uint w = red[j][t >> 1];
            S += (t & 1) ? (w >> 16) : (w & 0xFFFFu);
        }
        lg[t] = 0.25f * (float)(15488 - 2*(int)S) + bfc[t];
        float m = lg[0];
        #pragma unroll
        for (int o = 1; o < 10; ++o) m = fmaxf(m, lg[o]);
        float se = 0.f;
        #pragma unroll
        for (int o = 0; o < 10; ++o) se += expf(lg[o] - m);
        out[(size_t)img*10 + t] = lg[t] - m - logf(se);
    }
}

extern "C" void kernel_launch(void* const* d_in, const int* in_sizes, int n_in,
                              void* d_out, int out_size, void* d_ws, size_t ws_size,
                              hipStream_t stream)
{
    const float* x   = (const float*)d_in[0];
    const float* w1  = (const float*)d_in[1];
    const float* w2  = (const float*)d_in[2];
    const float* w3  = (const float*)d_in[3];
    const float* wfc = (const float*)d_in[4];
    const float* bfc = (const float*)d_in[5];
    float* out = (float*)d_out;
    uint* wsu  = (uint*)d_ws;

    const int B = in_sizes[0] / 784;   // 8192

    hipLaunchKernelGGL(pack_kernel, dim3(23), dim3(256), 0, stream,
                       w1, w2, w3, wfc, wsu);
    hipLaunchKernelGGL(binet_kernel, dim3(B), dim3(256), 0, stream,
                       x, wsu, bfc, out);
}